// Round 1
// baseline (355.853 us; speedup 1.0000x reference)
//
#include <hip/hip_runtime.h>
#include <hip/hip_bf16.h>

// B=2, D=1024, N=2048, H=16, DH=64
#define BATCH 2
#define DMODEL 1024
#define SEQ 2048
#define NHEAD 16
#define DHEAD 64
#define BH (BATCH*NHEAD)   // 32
#define COLS (BATCH*SEQ)   // 4096

typedef __attribute__((ext_vector_type(8))) short bf16x8;
typedef __attribute__((ext_vector_type(4))) float f32x4;

__device__ inline unsigned short f2bf(float f) {
    unsigned u = __builtin_bit_cast(unsigned, f);
    unsigned r = (u + 0x7FFFu + ((u >> 16) & 1u)) >> 16;
    return (unsigned short)r;
}

__device__ inline f32x4 mfma16(bf16x8 a, bf16x8 b, f32x4 c) {
    return __builtin_amdgcn_mfma_f32_16x16x32_bf16(a, b, c, 0, 0, 0);
}

// ---------------- convert 4 weight matrices fp32 -> bf16 ----------------
__global__ __launch_bounds__(256) void cvt_w(
    const float* __restrict__ w0, const float* __restrict__ w1,
    const float* __restrict__ w2, const float* __restrict__ w3,
    unsigned short* __restrict__ out)
{
    int which = blockIdx.y;
    const float* src = (which == 0) ? w0 : (which == 1) ? w1 : (which == 2) ? w2 : w3;
    size_t base = (size_t)which * (DMODEL * DMODEL);
    size_t i = ((size_t)blockIdx.x * 256 + threadIdx.x) * 4;
    float4 v = *(const float4*)&src[i];
    ushort4 o;
    o.x = f2bf(v.x); o.y = f2bf(v.y); o.z = f2bf(v.z); o.w = f2bf(v.w);
    *(ushort4*)&out[base + i] = o;
}

// ---------------- transpose query [B][D][N] fp32 -> Xt [B][N][D] bf16 ----------------
__global__ __launch_bounds__(256) void transpose_q(
    const float* __restrict__ q, unsigned short* __restrict__ Xt)
{
    __shared__ float tile[32][33];
    int b = blockIdx.z;
    int d0 = blockIdx.y * 32, n0 = blockIdx.x * 32;
    int tx = threadIdx.x, ty = threadIdx.y;  // 32 x 8
#pragma unroll
    for (int i = 0; i < 32; i += 8)
        tile[ty + i][tx] = q[(size_t)b * DMODEL * SEQ + (size_t)(d0 + ty + i) * SEQ + n0 + tx];
    __syncthreads();
#pragma unroll
    for (int i = 0; i < 32; i += 8)
        Xt[(size_t)b * SEQ * DMODEL + (size_t)(n0 + ty + i) * DMODEL + d0 + tx] = f2bf(tile[tx][ty + i]);
}

// ---------------- GEMM: OUT[e,c] = sum_d A[e,d]*Bt[c,d] + bias[e] ----------------
// A: [1024][1024] bf16 row-major, Bt: [4096][1024] bf16 row-major (k-contig both)
// MODE 0: Q  -> (v+b)*0.125 -> bf16 [BH][N][64]
// MODE 1: K  -> bf16 [BH][N][64]
// MODE 2: V  -> bf16 [BH][64][N] (transposed)
// MODE 3: O  -> fp32 [B][D][N]
template<int MODE>
__global__ __launch_bounds__(256) void gemm_bt(
    const unsigned short* __restrict__ A,
    const unsigned short* __restrict__ Bt,
    const float* __restrict__ bias,
    unsigned short* __restrict__ outb,
    float* __restrict__ outf)
{
    const int K = DMODEL;
    const int LDP = 40;  // padded LDS stride (ushorts): 80B rows -> 2-way bank aliasing only
    __shared__ unsigned short sA[128 * LDP];
    __shared__ unsigned short sB[128 * LDP];
    int t = threadIdx.x;
    int lane = t & 63, w = t >> 6;
    int wr = w >> 1, wc = w & 1;
    int et0 = blockIdx.y * 128, ct0 = blockIdx.x * 128;
    int rl = lane & 15, ko = (lane >> 4) << 3;

    f32x4 acc[4][4] = {};

    int sr = t >> 2, sc = (t & 3) << 3;   // staging: row t/4, col (t%4)*8
    for (int kb = 0; kb < K; kb += 32) {
        __syncthreads();
        *(uint4*)&sA[sr * LDP + sc]        = *(const uint4*)&A[(size_t)(et0 + sr) * K + kb + sc];
        *(uint4*)&sA[(sr + 64) * LDP + sc] = *(const uint4*)&A[(size_t)(et0 + 64 + sr) * K + kb + sc];
        *(uint4*)&sB[sr * LDP + sc]        = *(const uint4*)&Bt[(size_t)(ct0 + sr) * K + kb + sc];
        *(uint4*)&sB[(sr + 64) * LDP + sc] = *(const uint4*)&Bt[(size_t)(ct0 + 64 + sr) * K + kb + sc];
        __syncthreads();
        bf16x8 af[4], bf[4];
#pragma unroll
        for (int m = 0; m < 4; m++)
            af[m] = *(const bf16x8*)&sA[(wr * 64 + m * 16 + rl) * LDP + ko];
#pragma unroll
        for (int n = 0; n < 4; n++)
            bf[n] = *(const bf16x8*)&sB[(wc * 64 + n * 16 + rl) * LDP + ko];
#pragma unroll
        for (int m = 0; m < 4; m++)
#pragma unroll
            for (int n = 0; n < 4; n++)
                acc[m][n] = mfma16(af[m], bf[n], acc[m][n]);
    }

    int rowb = (lane >> 4) * 4;
    int col = lane & 15;
#pragma unroll
    for (int m = 0; m < 4; m++) {
#pragma unroll
        for (int n = 0; n < 4; n++) {
            int c = ct0 + wc * 64 + n * 16 + col;
            int b = c >> 11, nn = c & (SEQ - 1);
#pragma unroll
            for (int r = 0; r < 4; r++) {
                int e = et0 + wr * 64 + m * 16 + rowb + r;
                float v = acc[m][n][r] + bias[e];
                if (MODE == 0) {
                    v *= 0.125f;
                    outb[((size_t)(b * NHEAD + (e >> 6)) * SEQ + nn) * DHEAD + (e & 63)] = f2bf(v);
                } else if (MODE == 1) {
                    outb[((size_t)(b * NHEAD + (e >> 6)) * SEQ + nn) * DHEAD + (e & 63)] = f2bf(v);
                } else if (MODE == 2) {
                    outb[((size_t)(b * NHEAD + (e >> 6)) * DHEAD + (e & 63)) * SEQ + nn] = f2bf(v);
                } else {
                    outf[((size_t)b * DMODEL + e) * SEQ + nn] = v;
                }
            }
        }
    }
}

// ---------------- attention ----------------
// Q,K: [BH][SEQ][64] bf16 (Q pre-scaled by 1/8); Vt: [BH][64][SEQ] bf16
// mask: [B][SEQ] int32 (head bh uses row bh%B)  -> Zt: [B][SEQ][D] bf16
__global__ __launch_bounds__(256) void attn(
    const unsigned short* __restrict__ Q,
    const unsigned short* __restrict__ Kb,
    const unsigned short* __restrict__ Vt,
    const int* __restrict__ mask,
    unsigned short* __restrict__ Zt)
{
    const int LPP = 72;  // padded P stride
    __shared__ unsigned short sP[4][16 * LPP];
    int bh = blockIdx.y;
    int b = bh >> 4, h = bh & 15;
    int mb = bh % BATCH;
    int t = threadIdx.x, lane = t & 63, w = t >> 6;
    int q0 = blockIdx.x * 64 + w * 16;
    int rl = lane & 15, ko = (lane >> 4) << 3;
    const unsigned short* Qp = Q + (size_t)bh * SEQ * DHEAD;
    const unsigned short* Kp = Kb + (size_t)bh * SEQ * DHEAD;
    const unsigned short* Vp = Vt + (size_t)bh * DHEAD * SEQ;
    unsigned short* sPw = sP[w];

    bf16x8 qa0 = *(const bf16x8*)&Qp[(size_t)(q0 + rl) * DHEAD + ko];
    bf16x8 qa1 = *(const bf16x8*)&Qp[(size_t)(q0 + rl) * DHEAD + 32 + ko];

    f32x4 Y[4] = {};
    float m_[4], l_[4];
#pragma unroll
    for (int r = 0; r < 4; r++) { m_[r] = -1e30f; l_[r] = 0.f; }
    unsigned long long anyb = 0ull;

    for (int k0 = 0; k0 < SEQ; k0 += 64) {
        int mv = mask[mb * SEQ + k0 + lane];
        unsigned long long mbits = __ballot(mv != 0);
        anyb |= mbits;

        f32x4 S[4];
#pragma unroll
        for (int tt = 0; tt < 4; tt++) {
            bf16x8 kb0 = *(const bf16x8*)&Kp[(size_t)(k0 + tt * 16 + rl) * DHEAD + ko];
            bf16x8 kb1 = *(const bf16x8*)&Kp[(size_t)(k0 + tt * 16 + rl) * DHEAD + 32 + ko];
            f32x4 s = {};
            s = mfma16(qa0, kb0, s);
            s = mfma16(qa1, kb1, s);
            bool valid = (mbits >> (tt * 16 + rl)) & 1ull;
            if (!valid) {
#pragma unroll
                for (int r = 0; r < 4; r++) s[r] = -1e30f;
            }
            S[tt] = s;
        }

        // online softmax per q-row (reg r), reduce across 16-lane group
#pragma unroll
        for (int r = 0; r < 4; r++) {
            float mx = fmaxf(fmaxf(S[0][r], S[1][r]), fmaxf(S[2][r], S[3][r]));
#pragma unroll
            for (int d = 1; d < 16; d <<= 1) mx = fmaxf(mx, __shfl_xor(mx, d, 64));
            float nm = fmaxf(m_[r], mx);
            float al = __expf(m_[r] - nm);
            float sm = 0.f;
#pragma unroll
            for (int tt = 0; tt < 4; tt++) {
                float p = __expf(S[tt][r] - nm);
                S[tt][r] = p;
                sm += p;
            }
#pragma unroll
            for (int d = 1; d < 16; d <<= 1) sm += __shfl_xor(sm, d, 64);
            l_[r] = l_[r] * al + sm;
            m_[r] = nm;
#pragma unroll
            for (int td = 0; td < 4; td++) Y[td][r] *= al;
        }

        // stage P (bf16) to LDS: [q=16][k=64] padded
#pragma unroll
        for (int tt = 0; tt < 4; tt++)
#pragma unroll
            for (int r = 0; r < 4; r++)
                sPw[((lane >> 4) * 4 + r) * LPP + tt * 16 + rl] = f2bf(S[tt][r]);
        asm volatile("s_waitcnt lgkmcnt(0)" ::: "memory");

        // PV: Y[td] += P[16x64] * V[64 x 16(td)]
#pragma unroll
        for (int kk = 0; kk < 2; kk++) {
            bf16x8 pa = *(const bf16x8*)&sPw[rl * LPP + kk * 32 + ko];
#pragma unroll
            for (int td = 0; td < 4; td++) {
                bf16x8 vb = *(const bf16x8*)&Vp[(size_t)(td * 16 + rl) * SEQ + k0 + kk * 32 + ko];
                Y[td] = mfma16(pa, vb, Y[td]);
            }
        }
    }

    bool none = (anyb == 0ull);
#pragma unroll
    for (int td = 0; td < 4; td++) {
#pragma unroll
        for (int r = 0; r < 4; r++) {
            float inv = none ? 0.f : (1.f / l_[r]);
            int n = q0 + (lane >> 4) * 4 + r;
            Zt[((size_t)b * SEQ + n) * DMODEL + h * DHEAD + td * 16 + rl] = f2bf(Y[td][r] * inv);
        }
    }
}

extern "C" void kernel_launch(void* const* d_in, const int* in_sizes, int n_in,
                              void* d_out, int out_size, void* d_ws, size_t ws_size,
                              hipStream_t stream) {
    const float* query = (const float*)d_in[0];
    const float* Wq = (const float*)d_in[1];
    const float* bq = (const float*)d_in[2];
    const float* Wk = (const float*)d_in[3];
    const float* bk = (const float*)d_in[4];
    const float* Wv = (const float*)d_in[5];
    const float* bv = (const float*)d_in[6];
    const float* Wo = (const float*)d_in[7];
    const float* bo = (const float*)d_in[8];
    const int* mask = (const int*)d_in[9];
    float* out = (float*)d_out;

    char* ws = (char*)d_ws;
    unsigned short* Wb  = (unsigned short*)(ws);                     // 4 x 2MB = 8MB
    unsigned short* Xt  = (unsigned short*)(ws + ((size_t)8  << 20)); // 8MB
    unsigned short* Qb  = (unsigned short*)(ws + ((size_t)16 << 20)); // 8MB
    unsigned short* Kbuf= (unsigned short*)(ws + ((size_t)24 << 20)); // 8MB
    unsigned short* Vtb = (unsigned short*)(ws + ((size_t)32 << 20)); // 8MB
    unsigned short* Zt  = (unsigned short*)(ws + ((size_t)40 << 20)); // 8MB

    const size_t WSZ = (size_t)DMODEL * DMODEL;

    cvt_w<<<dim3(DMODEL * DMODEL / 1024, 4), 256, 0, stream>>>(Wq, Wk, Wv, Wo, Wb);
    transpose_q<<<dim3(SEQ / 32, DMODEL / 32, BATCH), dim3(32, 8), 0, stream>>>(query, Xt);

    dim3 ggrid(COLS / 128, DMODEL / 128);
    gemm_bt<0><<<ggrid, 256, 0, stream>>>(Wb + 0 * WSZ, Xt, bq, Qb,  nullptr);
    gemm_bt<1><<<ggrid, 256, 0, stream>>>(Wb + 1 * WSZ, Xt, bk, Kbuf, nullptr);
    gemm_bt<2><<<ggrid, 256, 0, stream>>>(Wb + 2 * WSZ, Xt, bv, Vtb, nullptr);

    attn<<<dim3(SEQ / 64, BH), 256, 0, stream>>>(Qb, Kbuf, Vtb, mask, Zt);

    gemm_bt<3><<<ggrid, 256, 0, stream>>>(Wb + 3 * WSZ, Zt, bo, nullptr, out);
}

// Round 2
// 221.283 us; speedup vs baseline: 1.6081x; 1.6081x over previous
//
#include <hip/hip_runtime.h>
#include <hip/hip_bf16.h>

// B=2, D=1024, N=2048, H=16, DH=64
#define BATCH 2
#define DMODEL 1024
#define SEQ 2048
#define NHEAD 16
#define DHEAD 64
#define BH (BATCH*NHEAD)   // 32
#define COLS (BATCH*SEQ)   // 4096

typedef __attribute__((ext_vector_type(8))) short bf16x8;
typedef __attribute__((ext_vector_type(4))) float f32x4;
typedef __attribute__((ext_vector_type(16))) float f32x16;

__device__ inline unsigned short f2bf(float f) {
    unsigned u = __builtin_bit_cast(unsigned, f);
    unsigned r = (u + 0x7FFFu + ((u >> 16) & 1u)) >> 16;
    return (unsigned short)r;
}

__device__ inline f32x4 mfma16(bf16x8 a, bf16x8 b, f32x4 c) {
    return __builtin_amdgcn_mfma_f32_16x16x32_bf16(a, b, c, 0, 0, 0);
}
__device__ inline f32x16 mfma32(bf16x8 a, bf16x8 b, f32x16 c) {
    return __builtin_amdgcn_mfma_f32_32x32x16_bf16(a, b, c, 0, 0, 0);
}

__device__ __forceinline__ void gload_lds16(const unsigned short* g, unsigned short* l) {
    __builtin_amdgcn_global_load_lds(
        (const __attribute__((address_space(1))) unsigned int*)g,
        (__attribute__((address_space(3))) unsigned int*)l, 16, 0, 0);
}

__device__ inline unsigned cvtpk(float lo, float hi) {
    unsigned r;
    asm("v_cvt_pk_bf16_f32 %0, %1, %2" : "=v"(r) : "v"(lo), "v"(hi));
    return r;
}

// ---------------- convert 4 weight matrices fp32 -> bf16 ----------------
__global__ __launch_bounds__(256) void cvt_w(
    const float* __restrict__ w0, const float* __restrict__ w1,
    const float* __restrict__ w2, const float* __restrict__ w3,
    unsigned short* __restrict__ out)
{
    int which = blockIdx.y;
    const float* src = (which == 0) ? w0 : (which == 1) ? w1 : (which == 2) ? w2 : w3;
    size_t base = (size_t)which * (DMODEL * DMODEL);
    size_t i = ((size_t)blockIdx.x * 256 + threadIdx.x) * 4;
    float4 v = *(const float4*)&src[i];
    ushort4 o;
    o.x = f2bf(v.x); o.y = f2bf(v.y); o.z = f2bf(v.z); o.w = f2bf(v.w);
    *(ushort4*)&out[base + i] = o;
}

// ---------------- transpose query [B][D][N] fp32 -> Xt [B][N][D] bf16 ----------------
__global__ __launch_bounds__(256) void transpose_q(
    const float* __restrict__ q, unsigned short* __restrict__ Xt)
{
    __shared__ float tile[32][33];
    int b = blockIdx.z;
    int d0 = blockIdx.y * 32, n0 = blockIdx.x * 32;
    int tx = threadIdx.x, ty = threadIdx.y;  // 32 x 8
#pragma unroll
    for (int i = 0; i < 32; i += 8)
        tile[ty + i][tx] = q[(size_t)b * DMODEL * SEQ + (size_t)(d0 + ty + i) * SEQ + n0 + tx];
    __syncthreads();
#pragma unroll
    for (int i = 0; i < 32; i += 8)
        Xt[(size_t)b * SEQ * DMODEL + (size_t)(n0 + ty + i) * DMODEL + d0 + tx] = f2bf(tile[tx][ty + i]);
}

// ---------------- GEMM: OUT[e,c] = sum_d A[e,d]*Bt[c,d] + bias[e] ----------------
// m97 structure: 128(M)x64(N) tile, BK=32, global_load_lds width 16, linear LDS.
// MODE 0: Q -> (v+b)*0.125 -> bf16 [BH][N][64]
// MODE 1: K -> bf16 [BH][N][64]
// MODE 2: V -> bf16 [BH][64][N] (transposed)
// MODE 3: O -> fp32 [B][D][N]
template<int MODE>
__global__ __launch_bounds__(256) void gemm_bt(
    const unsigned short* __restrict__ A,
    const unsigned short* __restrict__ Bt,
    const float* __restrict__ bias,
    unsigned short* __restrict__ outb,
    float* __restrict__ outf)
{
    const int K = DMODEL;
    __shared__ unsigned short sA[128 * 32];
    __shared__ unsigned short sB[64 * 32];
    int t = threadIdx.x;
    int lane = t & 63, w = t >> 6;
    int wr = w >> 1, wc = w & 1;
    int et0 = blockIdx.y * 128, ct0 = blockIdx.x * 64;
    int rl = lane & 15, ko = (lane >> 4) << 3;
    int srow = lane >> 2, scol = (lane & 3) << 3;

    f32x4 acc[4][2] = {};

    for (int kb = 0; kb < K; kb += 32) {
        __syncthreads();
        gload_lds16(&A[(size_t)(et0 + w * 16 + srow) * K + kb + scol],      &sA[(w * 16) * 32]);
        gload_lds16(&A[(size_t)(et0 + 64 + w * 16 + srow) * K + kb + scol], &sA[(64 + w * 16) * 32]);
        gload_lds16(&Bt[(size_t)(ct0 + w * 16 + srow) * K + kb + scol],     &sB[(w * 16) * 32]);
        __syncthreads();
        bf16x8 af[4], bfr[2];
#pragma unroll
        for (int m = 0; m < 4; m++)
            af[m] = *(const bf16x8*)&sA[(wr * 64 + m * 16 + rl) * 32 + ko];
#pragma unroll
        for (int n = 0; n < 2; n++)
            bfr[n] = *(const bf16x8*)&sB[(wc * 32 + n * 16 + rl) * 32 + ko];
#pragma unroll
        for (int m = 0; m < 4; m++)
#pragma unroll
            for (int n = 0; n < 2; n++)
                acc[m][n] = mfma16(af[m], bfr[n], acc[m][n]);
    }

    int rowb = (lane >> 4) * 4;
    int col = lane & 15;
#pragma unroll
    for (int m = 0; m < 4; m++) {
#pragma unroll
        for (int n = 0; n < 2; n++) {
            int c = ct0 + wc * 32 + n * 16 + col;
            int b = c >> 11, nn = c & (SEQ - 1);
#pragma unroll
            for (int r = 0; r < 4; r++) {
                int e = et0 + wr * 64 + m * 16 + rowb + r;
                float v = acc[m][n][r] + bias[e];
                if (MODE == 0) {
                    v *= 0.125f;
                    outb[((size_t)(b * NHEAD + (e >> 6)) * SEQ + nn) * DHEAD + (e & 63)] = f2bf(v);
                } else if (MODE == 1) {
                    outb[((size_t)(b * NHEAD + (e >> 6)) * SEQ + nn) * DHEAD + (e & 63)] = f2bf(v);
                } else if (MODE == 2) {
                    outb[((size_t)(b * NHEAD + (e >> 6)) * DHEAD + (e & 63)) * SEQ + nn] = f2bf(v);
                } else {
                    outf[((size_t)b * DMODEL + e) * SEQ + nn] = v;
                }
            }
        }
    }
}

// ---------------- attention: swapped-QK^T 32x32, in-register softmax ----------------
// Q,K: [BH][SEQ][64] bf16 (Q pre-scaled by 1/8); Vt: [BH][64][SEQ] bf16
// mask: [B][SEQ] int (head bh uses row bh%B) -> Zt: [B][SEQ][D] bf16
// Per wave: 32 q-rows. S = mfma(K, Q): col=q=lane&31, row=k=(reg&3)+8*(reg>>2)+4*hi.
__global__ __launch_bounds__(256) void attn(
    const unsigned short* __restrict__ Q,
    const unsigned short* __restrict__ Kb,
    const unsigned short* __restrict__ Vt,
    const int* __restrict__ mask,
    unsigned short* __restrict__ Zt)
{
    int bh = blockIdx.y;
    int b = bh >> 4, h = bh & 15;
    int mb = bh & (BATCH - 1);           // tile semantics: head bh uses mask row bh%B
    int t = threadIdx.x, lane = t & 63, w = t >> 6;
    int hi = lane >> 5, ql = lane & 31;
    int q0 = blockIdx.x * 128 + w * 32;
    const unsigned short* Qp = Q + (size_t)bh * SEQ * DHEAD;
    const unsigned short* Kp = Kb + (size_t)bh * SEQ * DHEAD;
    const unsigned short* Vp = Vt + (size_t)bh * DHEAD * SEQ;

    bf16x8 qf[4];
#pragma unroll
    for (int c = 0; c < 4; c++)
        qf[c] = *(const bf16x8*)&Qp[(size_t)(q0 + ql) * DHEAD + c * 16 + hi * 8];

    f32x16 Y0 = {}, Y1 = {};
    float m_ = -1e30f, l_ = 0.f;
    unsigned long long anyb = 0ull;

    for (int k0 = 0; k0 < SEQ; k0 += 64) {
        unsigned long long mbits = __ballot(mask[mb * SEQ + k0 + lane] != 0);
        anyb |= mbits;
        if (mbits == 0ull) continue;   // wave-uniform

        // QK^T swapped: S[k][q], k covers 64 via two 32-row tiles
        f32x16 S0 = {}, S1 = {};
#pragma unroll
        for (int c = 0; c < 4; c++) {
            bf16x8 kf = *(const bf16x8*)&Kp[(size_t)(k0 + ql) * DHEAD + c * 16 + hi * 8];
            S0 = mfma32(kf, qf[c], S0);
        }
#pragma unroll
        for (int c = 0; c < 4; c++) {
            bf16x8 kf = *(const bf16x8*)&Kp[(size_t)(k0 + 32 + ql) * DHEAD + c * 16 + hi * 8];
            S1 = mfma32(kf, qf[c], S1);
        }

        // in-lane max tree over 32 raw scores (masked values included: valid shift)
        float t0[16];
#pragma unroll
        for (int r = 0; r < 16; r++) t0[r] = fmaxf(S0[r], S1[r]);
#pragma unroll
        for (int s = 8; s > 0; s >>= 1)
#pragma unroll
            for (int r = 0; r < 8; r++)
                if (r < s) t0[r] = fmaxf(t0[r], t0[r + s]);
        float pmax = fmaxf(t0[0], __shfl_xor(t0[0], 32, 64));

        // defer-max (T13, THR=8): rescale only when some row grew past threshold
        float mnew = fmaxf(m_, pmax);
        if (!__all(pmax <= m_ + 8.0f)) {
            float al = __expf(m_ - mnew);
            m_ = mnew;
            l_ *= al;
#pragma unroll
            for (int reg = 0; reg < 16; reg++) {
                float av = __shfl(al, (reg & 3) + 8 * (reg >> 2) + 4 * hi, 64);
                Y0[reg] *= av;
                Y1[reg] *= av;
            }
        }

        // exp + mask-zero + partial sums (4 chains of 8 -> tree)
        unsigned long long msh = mbits >> (hi * 4);
        float p[32];
        float s4[4] = {0.f, 0.f, 0.f, 0.f};
#pragma unroll
        for (int tt = 0; tt < 2; tt++)
#pragma unroll
            for (int rr = 0; rr < 16; rr++) {
                const int bit = tt * 32 + (rr & 3) + 8 * (rr >> 2);
                float s = tt ? S1[rr] : S0[rr];
                float e = __expf(s - m_);
                e = ((msh >> bit) & 1ull) ? e : 0.f;
                p[tt * 16 + rr] = e;
                s4[rr & 3] += e;
            }
        float sm = (s4[0] + s4[1]) + (s4[2] + s4[3]);
        sm += __shfl_xor(sm, 32, 64);
        l_ += sm;

        // pack P -> bf16 pairs; cross-half exchange builds PV A-fragments
        unsigned PKa[8], PKb[8];
#pragma unroll
        for (int i = 0; i < 8; i++) {
            PKa[i] = cvtpk(p[4 * i], p[4 * i + 1]);
            PKb[i] = cvtpk(p[4 * i + 2], p[4 * i + 3]);
        }
        bf16x8 pa[4];
#pragma unroll
        for (int ks = 0; ks < 4; ks++) {
            unsigned ea = hi ? PKa[2 * ks] : PKa[2 * ks + 1];
            unsigned eb = hi ? PKb[2 * ks] : PKb[2 * ks + 1];
            unsigned ma = hi ? PKa[2 * ks + 1] : PKa[2 * ks];
            unsigned mbv = hi ? PKb[2 * ks + 1] : PKb[2 * ks];
            unsigned ra = (unsigned)__shfl_xor((int)ea, 32, 64);
            unsigned rb = (unsigned)__shfl_xor((int)eb, 32, 64);
            union { unsigned u[4]; bf16x8 v; } pu;
            pu.u[0] = hi ? ra : ma;
            pu.u[1] = hi ? rb : mbv;
            pu.u[2] = hi ? ma : ra;
            pu.u[3] = hi ? mbv : rb;
            pa[ks] = pu.v;
        }

        // PV: Y[q][d] += P[q][k] * Vt[d][k]
#pragma unroll
        for (int ks = 0; ks < 4; ks++) {
            bf16x8 vb0 = *(const bf16x8*)&Vp[(size_t)ql * SEQ + k0 + 16 * ks + 8 * hi];
            bf16x8 vb1 = *(const bf16x8*)&Vp[(size_t)(32 + ql) * SEQ + k0 + 16 * ks + 8 * hi];
            Y0 = mfma32(pa[ks], vb0, Y0);
            Y1 = mfma32(pa[ks], vb1, Y1);
        }
    }

    float linv = (anyb == 0ull) ? 0.f : (1.0f / l_);
#pragma unroll
    for (int reg = 0; reg < 16; reg++) {
        int row = (reg & 3) + 8 * (reg >> 2) + 4 * hi;
        float lv = __shfl(linv, row, 64);
        int n = q0 + row;
        size_t base = ((size_t)b * SEQ + n) * DMODEL + h * DHEAD;
        Zt[base + ql] = f2bf(Y0[reg] * lv);
        Zt[base + 32 + ql] = f2bf(Y1[reg] * lv);
    }
}

extern "C" void kernel_launch(void* const* d_in, const int* in_sizes, int n_in,
                              void* d_out, int out_size, void* d_ws, size_t ws_size,
                              hipStream_t stream) {
    const float* query = (const float*)d_in[0];
    const float* Wq = (const float*)d_in[1];
    const float* bq = (const float*)d_in[2];
    const float* Wk = (const float*)d_in[3];
    const float* bk = (const float*)d_in[4];
    const float* Wv = (const float*)d_in[5];
    const float* bv = (const float*)d_in[6];
    const float* Wo = (const float*)d_in[7];
    const float* bo = (const float*)d_in[8];
    const int* mask = (const int*)d_in[9];
    float* out = (float*)d_out;

    char* ws = (char*)d_ws;
    unsigned short* Wb  = (unsigned short*)(ws);                      // 8MB
    unsigned short* Xt  = (unsigned short*)(ws + ((size_t)8  << 20)); // 8MB
    unsigned short* Qb  = (unsigned short*)(ws + ((size_t)16 << 20)); // 8MB
    unsigned short* Kbuf= (unsigned short*)(ws + ((size_t)24 << 20)); // 8MB
    unsigned short* Vtb = (unsigned short*)(ws + ((size_t)32 << 20)); // 8MB
    unsigned short* Zt  = (unsigned short*)(ws + ((size_t)40 << 20)); // 8MB

    const size_t WSZ = (size_t)DMODEL * DMODEL;

    cvt_w<<<dim3(DMODEL * DMODEL / 1024, 4), 256, 0, stream>>>(Wq, Wk, Wv, Wo, Wb);
    transpose_q<<<dim3(SEQ / 32, DMODEL / 32, BATCH), dim3(32, 8), 0, stream>>>(query, Xt);

    dim3 ggrid(COLS / 64, DMODEL / 128);
    gemm_bt<0><<<ggrid, 256, 0, stream>>>(Wb + 0 * WSZ, Xt, bq, Qb,  nullptr);
    gemm_bt<1><<<ggrid, 256, 0, stream>>>(Wb + 1 * WSZ, Xt, bk, Kbuf, nullptr);
    gemm_bt<2><<<ggrid, 256, 0, stream>>>(Wb + 2 * WSZ, Xt, bv, Vtb, nullptr);

    attn<<<dim3(SEQ / 128, BH), 256, 0, stream>>>(Qb, Kbuf, Vtb, mask, Zt);

    gemm_bt<3><<<ggrid, 256, 0, stream>>>(Wb + 3 * WSZ, Zt, bo, nullptr, out);
}

// Round 3
// 197.296 us; speedup vs baseline: 1.8037x; 1.1216x over previous
//
#include <hip/hip_runtime.h>
#include <hip/hip_bf16.h>

// B=2, D=1024, N=2048, H=16, DH=64
#define BATCH 2
#define DMODEL 1024
#define SEQ 2048
#define NHEAD 16
#define DHEAD 64
#define BH (BATCH*NHEAD)   // 32
#define COLS (BATCH*SEQ)   // 4096

typedef __attribute__((ext_vector_type(8))) short bf16x8;
typedef __attribute__((ext_vector_type(4))) float f32x4;
typedef __attribute__((ext_vector_type(16))) float f32x16;

__device__ inline unsigned short f2bf(float f) {
    unsigned u = __builtin_bit_cast(unsigned, f);
    unsigned r = (u + 0x7FFFu + ((u >> 16) & 1u)) >> 16;
    return (unsigned short)r;
}

__device__ inline f32x4 mfma16(bf16x8 a, bf16x8 b, f32x4 c) {
    return __builtin_amdgcn_mfma_f32_16x16x32_bf16(a, b, c, 0, 0, 0);
}
__device__ inline f32x16 mfma32(bf16x8 a, bf16x8 b, f32x16 c) {
    return __builtin_amdgcn_mfma_f32_32x32x16_bf16(a, b, c, 0, 0, 0);
}

__device__ __forceinline__ void gload_lds16(const unsigned short* g, unsigned short* l) {
    __builtin_amdgcn_global_load_lds(
        (const __attribute__((address_space(1))) unsigned int*)g,
        (__attribute__((address_space(3))) unsigned int*)l, 16, 0, 0);
}

__device__ inline unsigned cvtpk(float lo, float hi) {
    unsigned r;
    asm("v_cvt_pk_bf16_f32 %0, %1, %2" : "=v"(r) : "v"(lo), "v"(hi));
    return r;
}

// ---------------- convert 4 weight matrices fp32 -> bf16 ----------------
__global__ __launch_bounds__(256) void cvt_w(
    const float* __restrict__ w0, const float* __restrict__ w1,
    const float* __restrict__ w2, const float* __restrict__ w3,
    unsigned short* __restrict__ out)
{
    int which = blockIdx.y;
    const float* src = (which == 0) ? w0 : (which == 1) ? w1 : (which == 2) ? w2 : w3;
    size_t base = (size_t)which * (DMODEL * DMODEL);
    size_t i = ((size_t)blockIdx.x * 256 + threadIdx.x) * 4;
    float4 v = *(const float4*)&src[i];
    ushort4 o;
    o.x = f2bf(v.x); o.y = f2bf(v.y); o.z = f2bf(v.z); o.w = f2bf(v.w);
    *(ushort4*)&out[base + i] = o;
}

// ---------------- mask -> per-tile 64-bit ballot words ----------------
__global__ __launch_bounds__(64) void prep_mask(
    const int* __restrict__ mask, unsigned long long* __restrict__ mw)
{
    int lane = threadIdx.x;
    int tile = blockIdx.x;            // [0,64): mb = tile>>5, tt = tile&31
    int mb = tile >> 5, tt = tile & 31;
    unsigned long long bits = __ballot(mask[mb * SEQ + tt * 64 + lane] != 0);
    if (lane == 0) mw[tile] = bits;
}

// ---------------- transpose query [B][D][N] fp32 -> Xt [B][N][D] bf16 ----------------
__global__ __launch_bounds__(256) void transpose_q(
    const float* __restrict__ q, unsigned short* __restrict__ Xt)
{
    __shared__ float tile[32][33];
    int b = blockIdx.z;
    int d0 = blockIdx.y * 32, n0 = blockIdx.x * 32;
    int tx = threadIdx.x, ty = threadIdx.y;  // 32 x 8
#pragma unroll
    for (int i = 0; i < 32; i += 8)
        tile[ty + i][tx] = q[(size_t)b * DMODEL * SEQ + (size_t)(d0 + ty + i) * SEQ + n0 + tx];
    __syncthreads();
#pragma unroll
    for (int i = 0; i < 32; i += 8)
        Xt[(size_t)b * SEQ * DMODEL + (size_t)(n0 + ty + i) * DMODEL + d0 + tx] = f2bf(tile[tx][ty + i]);
}

// ---------------- fused QKV GEMM, m97 128x128 structure ----------------
// OUT[c,e] = sum_d Xt[c,d]*W3[e,d] + bias[e],  c=token [0,4096), e=[0,3072) (Wq|Wk|Wv)
__global__ __launch_bounds__(256) void gemm_qkv(
    const unsigned short* __restrict__ Xt,   // [4096][1024]
    const unsigned short* __restrict__ W3,   // [3072][1024]
    const float* __restrict__ bq, const float* __restrict__ bk, const float* __restrict__ bv,
    unsigned short* __restrict__ Qb, unsigned short* __restrict__ Kbuf,
    unsigned short* __restrict__ Vtb)
{
    const int K = DMODEL;
    __shared__ unsigned short sA[128 * 32];
    __shared__ unsigned short sB[128 * 32];
    int t = threadIdx.x, lane = t & 63, w = t >> 6;
    int wr = w >> 1, wc = w & 1;
    int tt0 = blockIdx.y * 128;        // token tile
    int ct0 = blockIdx.x * 128;        // e tile within stacked 3072
    int mat = ct0 >> 10, ec0 = ct0 & 1023;
    const float* bs = (mat == 0) ? bq : (mat == 1) ? bk : bv;
    int rl = lane & 15, ko = (lane >> 4) << 3;
    int srow = lane >> 2, scol = (lane & 3) << 3;

    f32x4 acc[4][4] = {};
    for (int kb = 0; kb < K; kb += 32) {
        __syncthreads();
        gload_lds16(&Xt[(size_t)(tt0 + w * 32 + srow) * K + kb + scol],      &sA[(w * 32) * 32]);
        gload_lds16(&Xt[(size_t)(tt0 + w * 32 + 16 + srow) * K + kb + scol], &sA[(w * 32 + 16) * 32]);
        gload_lds16(&W3[(size_t)(ct0 + w * 32 + srow) * K + kb + scol],      &sB[(w * 32) * 32]);
        gload_lds16(&W3[(size_t)(ct0 + w * 32 + 16 + srow) * K + kb + scol], &sB[(w * 32 + 16) * 32]);
        __syncthreads();
        bf16x8 af[4], bfr[4];
#pragma unroll
        for (int m = 0; m < 4; m++)
            af[m] = *(const bf16x8*)&sA[(wr * 64 + m * 16 + rl) * 32 + ko];
#pragma unroll
        for (int n = 0; n < 4; n++)
            bfr[n] = *(const bf16x8*)&sB[(wc * 64 + n * 16 + rl) * 32 + ko];
#pragma unroll
        for (int m = 0; m < 4; m++)
#pragma unroll
            for (int n = 0; n < 4; n++)
                acc[m][n] = mfma16(af[m], bfr[n], acc[m][n]);
    }

    const float QS = 0.125f;
    int rowb = (lane >> 4) * 4, col = lane & 15;
#pragma unroll
    for (int m = 0; m < 4; m++) {
#pragma unroll
        for (int n = 0; n < 4; n++) {
            int ee = ec0 + wc * 64 + n * 16 + col;
            int hh = ee >> 6, dd = ee & 63;
            float bias = bs[ee];
#pragma unroll
            for (int r = 0; r < 4; r++) {
                int tk = tt0 + wr * 64 + m * 16 + rowb + r;
                int b = tk >> 11, nn = tk & (SEQ - 1);
                float v = acc[m][n][r] + bias;
                if (mat == 0) {
                    v *= QS;
                    Qb[((size_t)(b * NHEAD + hh) * SEQ + nn) * DHEAD + dd] = f2bf(v);
                } else if (mat == 1) {
                    Kbuf[((size_t)(b * NHEAD + hh) * SEQ + nn) * DHEAD + dd] = f2bf(v);
                } else {
                    Vtb[((size_t)(b * NHEAD + hh) * DHEAD + dd) * SEQ + nn] = f2bf(v);
                }
            }
        }
    }
}

// ---------------- output GEMM: out[e,c] = sum_d Wo[e,d]*Zt[c,d] + bo[e] ----------------
__global__ __launch_bounds__(256) void gemm_out(
    const unsigned short* __restrict__ A,    // Wo bf16 [1024][1024]
    const unsigned short* __restrict__ Bt,   // Zt [4096][1024]
    const float* __restrict__ bias,
    float* __restrict__ outf)
{
    const int K = DMODEL;
    __shared__ unsigned short sA[128 * 32];
    __shared__ unsigned short sB[64 * 32];
    int t = threadIdx.x, lane = t & 63, w = t >> 6;
    int wr = w >> 1, wc = w & 1;
    int et0 = blockIdx.y * 128, ct0 = blockIdx.x * 64;
    int rl = lane & 15, ko = (lane >> 4) << 3;
    int srow = lane >> 2, scol = (lane & 3) << 3;

    f32x4 acc[4][2] = {};
    for (int kb = 0; kb < K; kb += 32) {
        __syncthreads();
        gload_lds16(&A[(size_t)(et0 + w * 16 + srow) * K + kb + scol],      &sA[(w * 16) * 32]);
        gload_lds16(&A[(size_t)(et0 + 64 + w * 16 + srow) * K + kb + scol], &sA[(64 + w * 16) * 32]);
        gload_lds16(&Bt[(size_t)(ct0 + w * 16 + srow) * K + kb + scol],     &sB[(w * 16) * 32]);
        __syncthreads();
        bf16x8 af[4], bfr[2];
#pragma unroll
        for (int m = 0; m < 4; m++)
            af[m] = *(const bf16x8*)&sA[(wr * 64 + m * 16 + rl) * 32 + ko];
#pragma unroll
        for (int n = 0; n < 2; n++)
            bfr[n] = *(const bf16x8*)&sB[(wc * 32 + n * 16 + rl) * 32 + ko];
#pragma unroll
        for (int m = 0; m < 4; m++)
#pragma unroll
            for (int n = 0; n < 2; n++)
                acc[m][n] = mfma16(af[m], bfr[n], acc[m][n]);
    }

    int rowb = (lane >> 4) * 4, col = lane & 15;
#pragma unroll
    for (int m = 0; m < 4; m++) {
#pragma unroll
        for (int n = 0; n < 2; n++) {
            int c = ct0 + wc * 32 + n * 16 + col;
            int b = c >> 11, nn = c & (SEQ - 1);
#pragma unroll
            for (int r = 0; r < 4; r++) {
                int e = et0 + wr * 64 + m * 16 + rowb + r;
                outf[((size_t)b * DMODEL + e) * SEQ + nn] = acc[m][n][r] + bias[e];
            }
        }
    }
}

// ---------------- attention: swapped-QK^T 32x32, in-register softmax ----------------
// reg-double-buffered K/V prefetch; precomputed mask words; XCD-local heads.
__global__ __launch_bounds__(256, 2) void attn(
    const unsigned short* __restrict__ Q,
    const unsigned short* __restrict__ Kb,
    const unsigned short* __restrict__ Vt,
    const unsigned long long* __restrict__ mwords,
    unsigned short* __restrict__ Zt)
{
    int bid = blockIdx.x;                 // 512 blocks; i%8 -> XCD
    int xcd = bid & 7, slot = bid >> 3;
    int bh = xcd + 8 * (slot >> 4);       // 4 heads per XCD -> K/V fits per-XCD L2
    int qb = slot & 15;
    int b = bh >> 4, h = bh & 15;
    int mb = bh & (BATCH - 1);            // tile semantics: head bh uses mask row bh%B
    int t = threadIdx.x, lane = t & 63, w = t >> 6;
    int hi = lane >> 5, ql = lane & 31;
    int q0 = qb * 128 + w * 32;
    const unsigned short* Qp = Q + (size_t)bh * SEQ * DHEAD;
    const unsigned short* Kp = Kb + (size_t)bh * SEQ * DHEAD;
    const unsigned short* Vp = Vt + (size_t)bh * DHEAD * SEQ;
    const unsigned long long* mw = mwords + mb * 32;

    bf16x8 qf[4];
#pragma unroll
    for (int c = 0; c < 4; c++)
        qf[c] = *(const bf16x8*)&Qp[(size_t)(q0 + ql) * DHEAD + c * 16 + hi * 8];

    f32x16 Y0 = {}, Y1 = {};
    float m_ = -1e30f, l_ = 0.f;
    unsigned long long anyb = 0ull;

    bf16x8 kA[8], vA[8], kB[8], vB[8];

    auto LOADKV = [&](int k0, bf16x8* kd, bf16x8* vd) {
#pragma unroll
        for (int c = 0; c < 4; c++) {
            kd[c]     = *(const bf16x8*)&Kp[(size_t)(k0 + ql) * DHEAD + c * 16 + hi * 8];
            kd[4 + c] = *(const bf16x8*)&Kp[(size_t)(k0 + 32 + ql) * DHEAD + c * 16 + hi * 8];
            vd[c]     = *(const bf16x8*)&Vp[(size_t)ql * SEQ + k0 + c * 16 + hi * 8];
            vd[4 + c] = *(const bf16x8*)&Vp[(size_t)(32 + ql) * SEQ + k0 + c * 16 + hi * 8];
        }
    };

    auto STEP = [&](int k0, bf16x8* kc, bf16x8* vc) {
        unsigned long long mbits = mw[k0 >> 6];   // wave-uniform scalar load
        anyb |= mbits;

        f32x16 S0 = {}, S1 = {};
        __builtin_amdgcn_s_setprio(1);
#pragma unroll
        for (int c = 0; c < 4; c++) S0 = mfma32(kc[c], qf[c], S0);
#pragma unroll
        for (int c = 0; c < 4; c++) S1 = mfma32(kc[4 + c], qf[c], S1);
        __builtin_amdgcn_s_setprio(0);

        // in-lane max tree over 32 raw scores (masked included: valid shift)
        float t0[16];
#pragma unroll
        for (int r = 0; r < 16; r++) t0[r] = fmaxf(S0[r], S1[r]);
#pragma unroll
        for (int s = 8; s > 0; s >>= 1)
#pragma unroll
            for (int r = 0; r < 8; r++)
                if (r < s) t0[r] = fmaxf(t0[r], t0[r + s]);
        float pmax = fmaxf(t0[0], __shfl_xor(t0[0], 32, 64));

        // defer-max (T13): rescale only when a row grew past threshold
        float mnew = fmaxf(m_, pmax);
        if (!__all(pmax <= m_ + 8.0f)) {
            float al = __expf(m_ - mnew);
            m_ = mnew;
            l_ *= al;
#pragma unroll
            for (int reg = 0; reg < 16; reg++) {
                float av = __shfl(al, (reg & 3) + 8 * (reg >> 2) + 4 * hi, 64);
                Y0[reg] *= av;
                Y1[reg] *= av;
            }
        }

        // exp + mask-zero + partial sums
        unsigned long long msh = mbits >> (hi * 4);
        float p[32];
        float s4[4] = {0.f, 0.f, 0.f, 0.f};
#pragma unroll
        for (int tt = 0; tt < 2; tt++)
#pragma unroll
            for (int rr = 0; rr < 16; rr++) {
                const int bit = tt * 32 + (rr & 3) + 8 * (rr >> 2);
                float s = tt ? S1[rr] : S0[rr];
                float e = __expf(s - m_);
                e = ((msh >> bit) & 1ull) ? e : 0.f;
                p[tt * 16 + rr] = e;
                s4[rr & 3] += e;
            }
        float sm = (s4[0] + s4[1]) + (s4[2] + s4[3]);
        sm += __shfl_xor(sm, 32, 64);
        l_ += sm;

        // pack P -> bf16; cross-half exchange builds PV A-fragments
        unsigned PKa[8], PKb[8];
#pragma unroll
        for (int i = 0; i < 8; i++) {
            PKa[i] = cvtpk(p[4 * i], p[4 * i + 1]);
            PKb[i] = cvtpk(p[4 * i + 2], p[4 * i + 3]);
        }
        bf16x8 pa[4];
#pragma unroll
        for (int ks = 0; ks < 4; ks++) {
            unsigned ea = hi ? PKa[2 * ks] : PKa[2 * ks + 1];
            unsigned eb = hi ? PKb[2 * ks] : PKb[2 * ks + 1];
            unsigned ma = hi ? PKa[2 * ks + 1] : PKa[2 * ks];
            unsigned mbv = hi ? PKb[2 * ks + 1] : PKb[2 * ks];
            unsigned ra = (unsigned)__shfl_xor((int)ea, 32, 64);
            unsigned rb = (unsigned)__shfl_xor((int)eb, 32, 64);
            union { unsigned u[4]; bf16x8 v; } pu;
            pu.u[0] = hi ? ra : ma;
            pu.u[1] = hi ? rb : mbv;
            pu.u[2] = hi ? ma : ra;
            pu.u[3] = hi ? mbv : rb;
            pa[ks] = pu.v;
        }

        __builtin_amdgcn_s_setprio(1);
#pragma unroll
        for (int ks = 0; ks < 4; ks++) {
            Y0 = mfma32(pa[ks], vc[ks], Y0);
            Y1 = mfma32(pa[ks], vc[4 + ks], Y1);
        }
        __builtin_amdgcn_s_setprio(0);
    };

    LOADKV(0, kA, vA);
    for (int k0 = 0; k0 < SEQ; k0 += 128) {
        LOADKV(k0 + 64, kB, vB);
        STEP(k0, kA, vA);
        LOADKV((k0 + 128) & (SEQ - 1), kA, vA);   // wraps harmlessly on last iter
        STEP(k0 + 64, kB, vB);
    }

    float linv = (anyb == 0ull) ? 0.f : (1.0f / l_);
#pragma unroll
    for (int reg = 0; reg < 16; reg++) {
        int row = (reg & 3) + 8 * (reg >> 2) + 4 * hi;
        float lv = __shfl(linv, row, 64);
        int n = q0 + row;
        size_t base = ((size_t)b * SEQ + n) * DMODEL + h * DHEAD;
        Zt[base + ql] = f2bf(Y0[reg] * lv);
        Zt[base + 32 + ql] = f2bf(Y1[reg] * lv);
    }
}

extern "C" void kernel_launch(void* const* d_in, const int* in_sizes, int n_in,
                              void* d_out, int out_size, void* d_ws, size_t ws_size,
                              hipStream_t stream) {
    const float* query = (const float*)d_in[0];
    const float* Wq = (const float*)d_in[1];
    const float* bq = (const float*)d_in[2];
    const float* Wk = (const float*)d_in[3];
    const float* bk = (const float*)d_in[4];
    const float* Wv = (const float*)d_in[5];
    const float* bv = (const float*)d_in[6];
    const float* Wo = (const float*)d_in[7];
    const float* bo = (const float*)d_in[8];
    const int* mask = (const int*)d_in[9];
    float* out = (float*)d_out;

    char* ws = (char*)d_ws;
    unsigned short* Wb  = (unsigned short*)(ws);                      // 8MB (Wq|Wk|Wv|Wo)
    unsigned short* Xt  = (unsigned short*)(ws + ((size_t)8  << 20)); // 8MB
    unsigned short* Qb  = (unsigned short*)(ws + ((size_t)16 << 20)); // 8MB
    unsigned short* Kbuf= (unsigned short*)(ws + ((size_t)24 << 20)); // 8MB
    unsigned short* Vtb = (unsigned short*)(ws + ((size_t)32 << 20)); // 8MB
    unsigned short* Zt  = (unsigned short*)(ws + ((size_t)40 << 20)); // 8MB
    unsigned long long* mwords = (unsigned long long*)(ws + ((size_t)48 << 20)); // 512B

    const size_t WSZ = (size_t)DMODEL * DMODEL;

    cvt_w<<<dim3(DMODEL * DMODEL / 1024, 4), 256, 0, stream>>>(Wq, Wk, Wv, Wo, Wb);
    prep_mask<<<64, 64, 0, stream>>>(mask, mwords);
    transpose_q<<<dim3(SEQ / 32, DMODEL / 32, BATCH), dim3(32, 8), 0, stream>>>(query, Xt);

    gemm_qkv<<<dim3(3 * DMODEL / 128, COLS / 128), 256, 0, stream>>>(
        Xt, Wb, bq, bk, bv, Qb, Kbuf, Vtb);

    attn<<<512, 256, 0, stream>>>(Qb, Kbuf, Vtb, mwords, Zt);

    gemm_out<<<dim3(COLS / 64, DMODEL / 128), 256, 0, stream>>>(
        Wb + 3 * WSZ, Zt, bo, out);
}

// Round 4
// 197.229 us; speedup vs baseline: 1.8043x; 1.0003x over previous
//
#include <hip/hip_runtime.h>
#include <hip/hip_bf16.h>

// B=2, D=1024, N=2048, H=16, DH=64
#define BATCH 2
#define DMODEL 1024
#define SEQ 2048
#define NHEAD 16
#define DHEAD 64
#define BH (BATCH*NHEAD)   // 32
#define COLS (BATCH*SEQ)   // 4096

typedef __attribute__((ext_vector_type(8))) short bf16x8;
typedef __attribute__((ext_vector_type(4))) float f32x4;
typedef __attribute__((ext_vector_type(16))) float f32x16;

__device__ inline unsigned short f2bf(float f) {
    unsigned u = __builtin_bit_cast(unsigned, f);
    unsigned r = (u + 0x7FFFu + ((u >> 16) & 1u)) >> 16;
    return (unsigned short)r;
}

__device__ inline f32x4 mfma16(bf16x8 a, bf16x8 b, f32x4 c) {
    return __builtin_amdgcn_mfma_f32_16x16x32_bf16(a, b, c, 0, 0, 0);
}
__device__ inline f32x16 mfma32(bf16x8 a, bf16x8 b, f32x16 c) {
    return __builtin_amdgcn_mfma_f32_32x32x16_bf16(a, b, c, 0, 0, 0);
}

__device__ __forceinline__ void gload_lds16(const unsigned short* g, unsigned short* l) {
    __builtin_amdgcn_global_load_lds(
        (const __attribute__((address_space(1))) unsigned int*)g,
        (__attribute__((address_space(3))) unsigned int*)l, 16, 0, 0);
}

__device__ inline unsigned cvtpk(float lo, float hi) {
    unsigned r;
    asm("v_cvt_pk_bf16_f32 %0, %1, %2" : "=v"(r) : "v"(lo), "v"(hi));
    return r;
}
__device__ inline float fexp2(float x) {
    float r;
    asm("v_exp_f32 %0, %1" : "=v"(r) : "v"(x));
    return r;
}

// ---------------- convert 4 weight matrices fp32 -> bf16 ----------------
__global__ __launch_bounds__(256) void cvt_w(
    const float* __restrict__ w0, const float* __restrict__ w1,
    const float* __restrict__ w2, const float* __restrict__ w3,
    unsigned short* __restrict__ out)
{
    int which = blockIdx.y;
    const float* src = (which == 0) ? w0 : (which == 1) ? w1 : (which == 2) ? w2 : w3;
    size_t base = (size_t)which * (DMODEL * DMODEL);
    size_t i = ((size_t)blockIdx.x * 256 + threadIdx.x) * 4;
    float4 v = *(const float4*)&src[i];
    ushort4 o;
    o.x = f2bf(v.x); o.y = f2bf(v.y); o.z = f2bf(v.z); o.w = f2bf(v.w);
    *(ushort4*)&out[base + i] = o;
}

// ---------------- mask -> per-tile 64-bit ballot words ----------------
__global__ __launch_bounds__(64) void prep_mask(
    const int* __restrict__ mask, unsigned long long* __restrict__ mw)
{
    int lane = threadIdx.x;
    int tile = blockIdx.x;            // [0,64): mb = tile>>5, tt = tile&31
    int mb = tile >> 5, tt = tile & 31;
    unsigned long long bits = __ballot(mask[mb * SEQ + tt * 64 + lane] != 0);
    if (lane == 0) mw[tile] = bits;
}

// ---------------- transpose query [B][D][N] fp32 -> Xt [B][N][D] bf16 ----------------
__global__ __launch_bounds__(256) void transpose_q(
    const float* __restrict__ q, unsigned short* __restrict__ Xt)
{
    __shared__ float tile[32][33];
    int b = blockIdx.z;
    int d0 = blockIdx.y * 32, n0 = blockIdx.x * 32;
    int tx = threadIdx.x, ty = threadIdx.y;  // 32 x 8
#pragma unroll
    for (int i = 0; i < 32; i += 8)
        tile[ty + i][tx] = q[(size_t)b * DMODEL * SEQ + (size_t)(d0 + ty + i) * SEQ + n0 + tx];
    __syncthreads();
#pragma unroll
    for (int i = 0; i < 32; i += 8)
        Xt[(size_t)b * SEQ * DMODEL + (size_t)(n0 + ty + i) * DMODEL + d0 + tx] = f2bf(tile[tx][ty + i]);
}

// ---------------- fused QKV GEMM, m97 128x128 structure ----------------
__global__ __launch_bounds__(256) void gemm_qkv(
    const unsigned short* __restrict__ Xt,   // [4096][1024]
    const unsigned short* __restrict__ W3,   // [3072][1024]
    const float* __restrict__ bq, const float* __restrict__ bk, const float* __restrict__ bv,
    unsigned short* __restrict__ Qb, unsigned short* __restrict__ Kbuf,
    unsigned short* __restrict__ Vtb)
{
    const int K = DMODEL;
    __shared__ unsigned short sA[128 * 32];
    __shared__ unsigned short sB[128 * 32];
    int t = threadIdx.x, lane = t & 63, w = t >> 6;
    int wr = w >> 1, wc = w & 1;
    int tt0 = blockIdx.y * 128;        // token tile
    int ct0 = blockIdx.x * 128;        // e tile within stacked 3072
    int mat = ct0 >> 10, ec0 = ct0 & 1023;
    const float* bs = (mat == 0) ? bq : (mat == 1) ? bk : bv;
    int rl = lane & 15, ko = (lane >> 4) << 3;
    int srow = lane >> 2, scol = (lane & 3) << 3;

    f32x4 acc[4][4] = {};
    for (int kb = 0; kb < K; kb += 32) {
        __syncthreads();
        gload_lds16(&Xt[(size_t)(tt0 + w * 32 + srow) * K + kb + scol],      &sA[(w * 32) * 32]);
        gload_lds16(&Xt[(size_t)(tt0 + w * 32 + 16 + srow) * K + kb + scol], &sA[(w * 32 + 16) * 32]);
        gload_lds16(&W3[(size_t)(ct0 + w * 32 + srow) * K + kb + scol],      &sB[(w * 32) * 32]);
        gload_lds16(&W3[(size_t)(ct0 + w * 32 + 16 + srow) * K + kb + scol], &sB[(w * 32 + 16) * 32]);
        __syncthreads();
        bf16x8 af[4], bfr[4];
#pragma unroll
        for (int m = 0; m < 4; m++)
            af[m] = *(const bf16x8*)&sA[(wr * 64 + m * 16 + rl) * 32 + ko];
#pragma unroll
        for (int n = 0; n < 4; n++)
            bfr[n] = *(const bf16x8*)&sB[(wc * 64 + n * 16 + rl) * 32 + ko];
#pragma unroll
        for (int m = 0; m < 4; m++)
#pragma unroll
            for (int n = 0; n < 4; n++)
                acc[m][n] = mfma16(af[m], bfr[n], acc[m][n]);
    }

    const float QS = 0.125f;
    int rowb = (lane >> 4) * 4, col = lane & 15;
#pragma unroll
    for (int m = 0; m < 4; m++) {
#pragma unroll
        for (int n = 0; n < 4; n++) {
            int ee = ec0 + wc * 64 + n * 16 + col;
            int hh = ee >> 6, dd = ee & 63;
            float bias = bs[ee];
#pragma unroll
            for (int r = 0; r < 4; r++) {
                int tk = tt0 + wr * 64 + m * 16 + rowb + r;
                int b = tk >> 11, nn = tk & (SEQ - 1);
                float v = acc[m][n][r] + bias;
                if (mat == 0) {
                    v *= QS;
                    Qb[((size_t)(b * NHEAD + hh) * SEQ + nn) * DHEAD + dd] = f2bf(v);
                } else if (mat == 1) {
                    Kbuf[((size_t)(b * NHEAD + hh) * SEQ + nn) * DHEAD + dd] = f2bf(v);
                } else {
                    Vtb[((size_t)(b * NHEAD + hh) * DHEAD + dd) * SEQ + nn] = f2bf(v);
                }
            }
        }
    }
}

// ---------------- output GEMM: out[e,c] = sum_d Wo[e,d]*Zt[c,d] + bo[e] ----------------
__global__ __launch_bounds__(256) void gemm_out(
    const unsigned short* __restrict__ A,    // Wo bf16 [1024][1024]
    const unsigned short* __restrict__ Bt,   // Zt [4096][1024]
    const float* __restrict__ bias,
    float* __restrict__ outf)
{
    const int K = DMODEL;
    __shared__ unsigned short sA[128 * 32];
    __shared__ unsigned short sB[64 * 32];
    int t = threadIdx.x, lane = t & 63, w = t >> 6;
    int wr = w >> 1, wc = w & 1;
    int et0 = blockIdx.y * 128, ct0 = blockIdx.x * 64;
    int rl = lane & 15, ko = (lane >> 4) << 3;
    int srow = lane >> 2, scol = (lane & 3) << 3;

    f32x4 acc[4][2] = {};
    for (int kb = 0; kb < K; kb += 32) {
        __syncthreads();
        gload_lds16(&A[(size_t)(et0 + w * 16 + srow) * K + kb + scol],      &sA[(w * 16) * 32]);
        gload_lds16(&A[(size_t)(et0 + 64 + w * 16 + srow) * K + kb + scol], &sA[(64 + w * 16) * 32]);
        gload_lds16(&Bt[(size_t)(ct0 + w * 16 + srow) * K + kb + scol],     &sB[(w * 16) * 32]);
        __syncthreads();
        bf16x8 af[4], bfr[2];
#pragma unroll
        for (int m = 0; m < 4; m++)
            af[m] = *(const bf16x8*)&sA[(wr * 64 + m * 16 + rl) * 32 + ko];
#pragma unroll
        for (int n = 0; n < 2; n++)
            bfr[n] = *(const bf16x8*)&sB[(wc * 32 + n * 16 + rl) * 32 + ko];
#pragma unroll
        for (int m = 0; m < 4; m++)
#pragma unroll
            for (int n = 0; n < 2; n++)
                acc[m][n] = mfma16(af[m], bfr[n], acc[m][n]);
    }

    int rowb = (lane >> 4) * 4, col = lane & 15;
#pragma unroll
    for (int m = 0; m < 4; m++) {
#pragma unroll
        for (int n = 0; n < 2; n++) {
            int c = ct0 + wc * 32 + n * 16 + col;
            int b = c >> 11, nn = c & (SEQ - 1);
#pragma unroll
            for (int r = 0; r < 4; r++) {
                int e = et0 + wr * 64 + m * 16 + rowb + r;
                outf[((size_t)b * DMODEL + e) * SEQ + nn] = acc[m][n][r] + bias[e];
            }
        }
    }
}

// ---------------- attention: split-K, 8 waves/block, in-register softmax ----------------
// waves 0-3: q-tiles, K in [0,1024); waves 4-7: same q-tiles, K in [1024,2048).
// Merge partial (m,l,Y) via LDS at the end.
__global__ __launch_bounds__(512, 4) void attn(
    const unsigned short* __restrict__ Q,
    const unsigned short* __restrict__ Kb,
    const unsigned short* __restrict__ Vt,
    const unsigned long long* __restrict__ mwords,
    unsigned short* __restrict__ Zt)
{
    __shared__ float lds_y[4][64][32];   // upper-half Y (32 KB)
    __shared__ float lds_ml[4][64][2];   // upper-half m,l (2 KB)

    int bid = blockIdx.x;                 // 512 blocks; bid%8 -> XCD
    int xcd = bid & 7, slot = bid >> 3;
    int bh = xcd + 8 * (slot >> 4);       // 4 heads per XCD -> K/V fits per-XCD L2
    int qb = slot & 15;
    int b = bh >> 4, h = bh & 15;
    int mb = bh & (BATCH - 1);            // tile semantics: head bh uses mask row bh%B
    int t = threadIdx.x, lane = t & 63, w = t >> 6;
    int qw = w & 3, kh = w >> 2;
    int hi = lane >> 5, ql = lane & 31;
    int q0 = qb * 128 + qw * 32;
    const unsigned short* Qp = Q + (size_t)bh * SEQ * DHEAD;
    const unsigned short* Kp = Kb + (size_t)bh * SEQ * DHEAD;
    const unsigned short* Vp = Vt + (size_t)bh * DHEAD * SEQ;
    const unsigned long long* mw = mwords + mb * 32;

    // full-range fully-masked detection (uniform scalar loads)
    unsigned long long anyb = 0ull;
#pragma unroll
    for (int i = 0; i < 32; i++) anyb |= mw[i];

    bf16x8 qf[4];
#pragma unroll
    for (int c = 0; c < 4; c++)
        qf[c] = *(const bf16x8*)&Qp[(size_t)(q0 + ql) * DHEAD + c * 16 + hi * 8];

    f32x16 Y0 = {}, Y1 = {};
    float m_ = -1e30f, l_ = 0.f;
    const float LOG2E = 1.442695041f;

    int kbase = kh * (SEQ / 2);
    for (int k0 = kbase; k0 < kbase + SEQ / 2; k0 += 64) {
        unsigned long long mbits = mw[k0 >> 6];   // wave-uniform scalar load
        if (mbits == 0ull) continue;

        // QK^T swapped: S[k][q]
        f32x16 S0 = {}, S1 = {};
        __builtin_amdgcn_s_setprio(1);
#pragma unroll
        for (int c = 0; c < 4; c++) {
            bf16x8 kf = *(const bf16x8*)&Kp[(size_t)(k0 + ql) * DHEAD + c * 16 + hi * 8];
            S0 = mfma32(kf, qf[c], S0);
        }
#pragma unroll
        for (int c = 0; c < 4; c++) {
            bf16x8 kf = *(const bf16x8*)&Kp[(size_t)(k0 + 32 + ql) * DHEAD + c * 16 + hi * 8];
            S1 = mfma32(kf, qf[c], S1);
        }
        __builtin_amdgcn_s_setprio(0);

        // in-lane max tree over 32 raw scores (masked included: valid shift)
        float t0[16];
#pragma unroll
        for (int r = 0; r < 16; r++) t0[r] = fmaxf(S0[r], S1[r]);
#pragma unroll
        for (int s = 8; s > 0; s >>= 1)
#pragma unroll
            for (int r = 0; r < 8; r++)
                if (r < s) t0[r] = fmaxf(t0[r], t0[r + s]);
        float pmax = fmaxf(t0[0], __shfl_xor(t0[0], 32, 64));

        // defer-max (T13): rescale only when a row grew past threshold
        float mnew = fmaxf(m_, pmax);
        if (!__all(pmax <= m_ + 8.0f)) {
            float al = __expf(m_ - mnew);
            m_ = mnew;
            l_ *= al;
#pragma unroll
            for (int reg = 0; reg < 16; reg++) {
                float av = __shfl(al, (reg & 3) + 8 * (reg >> 2) + 4 * hi, 64);
                Y0[reg] *= av;
                Y1[reg] *= av;
            }
        }

        // exp2 + sign-extend mask AND + partial sums
        unsigned long long msh = mbits >> (hi * 4);
        unsigned w0m = (unsigned)msh, w1m = (unsigned)(msh >> 32);
        float nmL = -m_ * LOG2E;
        float p[32];
        float s4[4] = {0.f, 0.f, 0.f, 0.f};
#pragma unroll
        for (int tt = 0; tt < 2; tt++)
#pragma unroll
            for (int rr = 0; rr < 16; rr++) {
                const int bpos = (rr & 3) + 8 * (rr >> 2);   // 0..27
                unsigned mm = tt ? w1m : w0m;
                unsigned sg = (unsigned)((int)(mm << (31 - bpos)) >> 31);
                float s = tt ? S1[rr] : S0[rr];
                float e = fexp2(fmaf(s, LOG2E, nmL));
                e = __builtin_bit_cast(float, __builtin_bit_cast(unsigned, e) & sg);
                p[tt * 16 + rr] = e;
                s4[rr & 3] += e;
            }
        float sm = (s4[0] + s4[1]) + (s4[2] + s4[3]);
        sm += __shfl_xor(sm, 32, 64);
        l_ += sm;

        // pack P -> bf16; cross-half exchange builds PV A-fragments
        unsigned PKa[8], PKb[8];
#pragma unroll
        for (int i = 0; i < 8; i++) {
            PKa[i] = cvtpk(p[4 * i], p[4 * i + 1]);
            PKb[i] = cvtpk(p[4 * i + 2], p[4 * i + 3]);
        }
        bf16x8 pa[4];
#pragma unroll
        for (int ks = 0; ks < 4; ks++) {
            unsigned ea = hi ? PKa[2 * ks] : PKa[2 * ks + 1];
            unsigned eb = hi ? PKb[2 * ks] : PKb[2 * ks + 1];
            unsigned ma = hi ? PKa[2 * ks + 1] : PKa[2 * ks];
            unsigned mbv = hi ? PKb[2 * ks + 1] : PKb[2 * ks];
            unsigned ra = (unsigned)__shfl_xor((int)ea, 32, 64);
            unsigned rb = (unsigned)__shfl_xor((int)eb, 32, 64);
            union { unsigned u[4]; bf16x8 v; } pu;
            pu.u[0] = hi ? ra : ma;
            pu.u[1] = hi ? rb : mbv;
            pu.u[2] = hi ? ma : ra;
            pu.u[3] = hi ? mbv : rb;
            pa[ks] = pu.v;
        }

        // PV: Y[q][d] += P[q][k] * Vt[d][k]
        __builtin_amdgcn_s_setprio(1);
#pragma unroll
        for (int ks = 0; ks < 4; ks++) {
            bf16x8 vb0 = *(const bf16x8*)&Vp[(size_t)ql * SEQ + k0 + 16 * ks + 8 * hi];
            bf16x8 vb1 = *(const bf16x8*)&Vp[(size_t)(32 + ql) * SEQ + k0 + 16 * ks + 8 * hi];
            Y0 = mfma32(pa[ks], vb0, Y0);
            Y1 = mfma32(pa[ks], vb1, Y1);
        }
        __builtin_amdgcn_s_setprio(0);
    }

    // ---- split-K merge ----
    if (kh == 1) {
#pragma unroll
        for (int reg = 0; reg < 16; reg++) {
            lds_y[qw][lane][reg] = Y0[reg];
            lds_y[qw][lane][16 + reg] = Y1[reg];
        }
        lds_ml[qw][lane][0] = m_;
        lds_ml[qw][lane][1] = l_;
    }
    __syncthreads();
    if (kh == 0) {
        float mB = lds_ml[qw][lane][0], lB = lds_ml[qw][lane][1];
        float ms = fmaxf(m_, mB);
        float aA = __expf(m_ - ms), aB = __expf(mB - ms);
        float l = l_ * aA + lB * aB;
        float linv = (anyb != 0ull) ? (1.0f / l) : 0.f;
        float za = aA * linv, zb = aB * linv;
#pragma unroll
        for (int reg = 0; reg < 16; reg++) {
            int row = (reg & 3) + 8 * (reg >> 2) + 4 * hi;
            float zav = __shfl(za, row, 64);
            float zbv = __shfl(zb, row, 64);
            float yB0 = lds_y[qw][lane][reg];
            float yB1 = lds_y[qw][lane][16 + reg];
            int n = q0 + row;
            size_t base = ((size_t)b * SEQ + n) * DMODEL + h * DHEAD;
            Zt[base + ql] = f2bf(Y0[reg] * zav + yB0 * zbv);
            Zt[base + 32 + ql] = f2bf(Y1[reg] * zav + yB1 * zbv);
        }
    }
}

extern "C" void kernel_launch(void* const* d_in, const int* in_sizes, int n_in,
                              void* d_out, int out_size, void* d_ws, size_t ws_size,
                              hipStream_t stream) {
    const float* query = (const float*)d_in[0];
    const float* Wq = (const float*)d_in[1];
    const float* bq = (const float*)d_in[2];
    const float* Wk = (const float*)d_in[3];
    const float* bk = (const float*)d_in[4];
    const float* Wv = (const float*)d_in[5];
    const float* bv = (const float*)d_in[6];
    const float* Wo = (const float*)d_in[7];
    const float* bo = (const float*)d_in[8];
    const int* mask = (const int*)d_in[9];
    float* out = (float*)d_out;

    char* ws = (char*)d_ws;
    unsigned short* Wb  = (unsigned short*)(ws);                      // 8MB (Wq|Wk|Wv|Wo)
    unsigned short* Xt  = (unsigned short*)(ws + ((size_t)8  << 20)); // 8MB
    unsigned short* Qb  = (unsigned short*)(ws + ((size_t)16 << 20)); // 8MB
    unsigned short* Kbuf= (unsigned short*)(ws + ((size_t)24 << 20)); // 8MB
    unsigned short* Vtb = (unsigned short*)(ws + ((size_t)32 << 20)); // 8MB
    unsigned short* Zt  = (unsigned short*)(ws + ((size_t)40 << 20)); // 8MB
    unsigned long long* mwords = (unsigned long long*)(ws + ((size_t)48 << 20)); // 512B

    const size_t WSZ = (size_t)DMODEL * DMODEL;

    cvt_w<<<dim3(DMODEL * DMODEL / 1024, 4), 256, 0, stream>>>(Wq, Wk, Wv, Wo, Wb);
    prep_mask<<<64, 64, 0, stream>>>(mask, mwords);
    transpose_q<<<dim3(SEQ / 32, DMODEL / 32, BATCH), dim3(32, 8), 0, stream>>>(query, Xt);

    gemm_qkv<<<dim3(3 * DMODEL / 128, COLS / 128), 256, 0, stream>>>(
        Xt, Wb, bq, bk, bv, Qb, Kbuf, Vtb);

    attn<<<512, 512, 0, stream>>>(Qb, Kbuf, Vtb, mwords, Zt);

    gemm_out<<<dim3(COLS / 64, DMODEL / 128), 256, 0, stream>>>(
        Wb + 3 * WSZ, Zt, bo, out);
}